// Round 7
// baseline (81.178 us; speedup 1.0000x reference)
//
#include <hip/hip_runtime.h>

#define NB   8192
#define NT   2048
#define OBS  30
#define LCH  64               // chunk length
#define CCH  32               // chunks per row (LCH*CCH == NT)
#define NCHAIN (NB*CCH)       // 262144 chains
#define NBLK   (NCHAIN/256)   // 1024 work blocks
#define TS   257              // transposed LDS stride; 257%32==1 -> <=2-way banks

// passA writes particular chunk-final states -> g_ps (scan reads only).
// scan writes true chunk-start states -> g_s (passC reads). Distinct arrays:
// no alias-forced ordering on the scan's serial path. Layout [(b*CCH+c)*32+k].
__device__ float g_ps[(size_t)NCHAIN * 32];
__device__ float g_s [(size_t)NCHAIN * 32];
__device__ float g_A [OBS * 32];   // A^64: g_A[i*32+j]; cols 30,31 are zero

// One recurrence step on a 32-slot register ring, 6 accumulator chains.
// Invariant: before step t, state s_t[i] lives at r[(t+i)&31], i=0..29.
// j == t mod 32 must be a compile-time constant (callers fully unroll).
__device__ __forceinline__ float step6(float (&r)[32], const float (&wx)[OBS],
                                       int j, float uwf) {
  float a0 = fmaf(wx[0], r[(j + 0) & 31], uwf);
  float a1 = wx[1] * r[(j + 1) & 31];
  float a2 = wx[2] * r[(j + 2) & 31];
  float a3 = wx[3] * r[(j + 3) & 31];
  float a4 = wx[4] * r[(j + 4) & 31];
  float a5 = wx[5] * r[(j + 5) & 31];
  #pragma unroll
  for (int i = 6; i < OBS; i += 6) {
    a0 = fmaf(wx[i],     r[(j + i)     & 31], a0);
    a1 = fmaf(wx[i + 1], r[(j + i + 1) & 31], a1);
    a2 = fmaf(wx[i + 2], r[(j + i + 2) & 31], a2);
    a3 = fmaf(wx[i + 3], r[(j + i + 3) & 31], a3);
    a4 = fmaf(wx[i + 4], r[(j + i + 4) & 31], a4);
    a5 = fmaf(wx[i + 5], r[(j + i + 5) & 31], a5);
  }
  float out = ((a0 + a1) + (a2 + a3)) + (a4 + a5);
  r[(j + 30) & 31] = out;   // becomes s_{t+1}[29]
  return out;
}

// A^64 via 30 unit-state homogeneous chains (lanes 0..31 of one extra block).
// Lanes k>=30 start from zero state -> columns 30,31 of g_A are written zero.
__device__ __forceinline__ void compute_A64(const float* __restrict__ Wx) {
  const int k = threadIdx.x;
  float wx[OBS];
  #pragma unroll
  for (int i = 0; i < OBS; ++i) wx[i] = Wx[i];
  float r[32];
  #pragma unroll
  for (int i = 0; i < 32; ++i) r[i] = (k < OBS && i == k) ? 1.f : 0.f;
  #pragma unroll
  for (int j = 0; j < 32; ++j) step6(r, wx, j, 0.f);
  #pragma unroll
  for (int j = 0; j < 32; ++j) {
    float o = step6(r, wx, j, 0.f);          // global step t = 32 + j
    if (j >= 2) g_A[(j - 2) * 32 + k] = o;   // rows 0..29
  }
}

// ---- pass A: zero-init chunk recurrence -> particular final states p_c ----
__global__ void __launch_bounds__(256, 4) k_passA(const float* __restrict__ u,
                                                  const float* __restrict__ Wx,
                                                  const float* __restrict__ Wf) {
  if (blockIdx.x == NBLK) { if (threadIdx.x < 32) compute_A64(Wx); return; }
  __shared__ float lds[32 * TS];      // 32.9 KB -> 4 blocks/CU
  const int t  = threadIdx.x;
  const int n0 = blockIdx.x * 256;
  float wx[OBS];
  #pragma unroll
  for (int i = 0; i < OBS; ++i) wx[i] = Wx[i];
  const float wf = Wf[0];
  float r[32];
  #pragma unroll
  for (int i = 0; i < 32; ++i) r[i] = 0.f;

  #pragma unroll
  for (int R = 0; R < 2; ++R) {
    const int S = R * 32;
    // stage u transposed: lds[step][chain], all banks <=2-way
    #pragma unroll
    for (int i = 0; i < 8; ++i) {
      int f = i * 256 + t, ch = f >> 3, q = f & 7;
      float4 v = *(const float4*)(u + (size_t)(n0 + ch) * LCH + S + 4 * q);
      lds[(4 * q + 0) * TS + ch] = v.x;
      lds[(4 * q + 1) * TS + ch] = v.y;
      lds[(4 * q + 2) * TS + ch] = v.z;
      lds[(4 * q + 3) * TS + ch] = v.w;
    }
    __syncthreads();
    #pragma unroll
    for (int s = 0; s < 32; ++s)
      step6(r, wx, s, wf * lds[s * TS + t]);   // bank (s+t)%32: 2-way, free
    __syncthreads();
  }
  // route states transposed -> fully coalesced g_ps write
  #pragma unroll
  for (int k = 0; k < 32; ++k) lds[k * TS + t] = r[k];
  __syncthreads();
  #pragma unroll
  for (int i = 0; i < 8; ++i) {
    int f = i * 256 + t, ch = f >> 3, q = f & 7;
    float4 w = make_float4(lds[(4 * q + 0) * TS + ch], lds[(4 * q + 1) * TS + ch],
                           lds[(4 * q + 2) * TS + ch], lds[(4 * q + 3) * TS + ch]);
    *(float4*)(g_ps + (size_t)(n0 + ch) * 32 + 4 * q) = w;
  }
}

// ---- scan: s_{c+1} = A^64 s_c + p_c; p from g_ps, s into g_s ----
// 32 lanes per batch row; cross-lane via per-group LDS slot (wave-synchronous,
// no barrier). No aliasing between p loads and s stores -> prefetch floats.
__global__ void __launch_bounds__(256, 4) k_scan(const float* __restrict__ x0) {
  __shared__ float sbuf[8 * 32];
  const int tid = blockIdx.x * 256 + threadIdx.x;
  const int b = tid >> 5;
  const int g = threadIdx.x >> 5;
  const int k = threadIdx.x & 31;
  float* sb = &sbuf[g * 32];

  float ar[32];
  #pragma unroll
  for (int j = 0; j < 32; ++j)
    ar[j] = (k < OBS) ? g_A[k * 32 + j] : 0.f;   // cols 30,31 genuinely zero
  float s = (k < OBS) ? x0[(size_t)b * OBS + k] : 0.f;
  const size_t base = (size_t)b * CCH * 32 + k;
  float pn0 = g_ps[base];
  float pn1 = g_ps[base + 32];

  #pragma unroll 1
  for (int c = 0; c < CCH; ++c) {
    float p = pn0;
    pn0 = pn1;
    int cn = (c + 2 < CCH) ? c + 2 : CCH - 1;
    pn1 = g_ps[base + (size_t)cn * 32];      // distance-2 prefetch, no alias
    sb[k] = s;                               // publish own component
    g_s[base + (size_t)c * 32] = s;          // persist s_c (write-only array)
    float a0, a1, a2, a3;
    {
      float4 v = *(const float4*)(&sb[0]);   // broadcast: conflict-free
      a0 = fmaf(ar[0], v.x, p);
      a1 = ar[1] * v.y;
      a2 = ar[2] * v.z;
      a3 = ar[3] * v.w;
    }
    #pragma unroll
    for (int q = 1; q < 8; ++q) {
      float4 v = *(const float4*)(&sb[4 * q]);
      a0 = fmaf(ar[4 * q + 0], v.x, a0);
      a1 = fmaf(ar[4 * q + 1], v.y, a1);
      a2 = fmaf(ar[4 * q + 2], v.z, a2);
      a3 = fmaf(ar[4 * q + 3], v.w, a3);
    }
    s = (a0 + a1) + (a2 + a3);
    // lanes k>=30: ar==0 -> s = p (junk-but-finite), never contaminates dots
  }
}

// ---- pass C: re-run each chunk from true start state, write outputs ----
__global__ void __launch_bounds__(256, 4) k_passC(const float* __restrict__ u,
                                                  const float* __restrict__ Wx,
                                                  const float* __restrict__ Wf,
                                                  float* __restrict__ out) {
  __shared__ float lds[32 * TS];
  const int t  = threadIdx.x;
  const int n0 = blockIdx.x * 256;
  float wx[OBS];
  #pragma unroll
  for (int i = 0; i < OBS; ++i) wx[i] = Wx[i];
  const float wf = Wf[0];

  // coalesced start-state load, routed transposed
  #pragma unroll
  for (int i = 0; i < 8; ++i) {
    int f = i * 256 + t, ch = f >> 3, q = f & 7;
    float4 v = *(const float4*)(g_s + (size_t)(n0 + ch) * 32 + 4 * q);
    lds[(4 * q + 0) * TS + ch] = v.x;
    lds[(4 * q + 1) * TS + ch] = v.y;
    lds[(4 * q + 2) * TS + ch] = v.z;
    lds[(4 * q + 3) * TS + ch] = v.w;
  }
  __syncthreads();
  float r[32];
  #pragma unroll
  for (int k = 0; k < 32; ++k) r[k] = lds[k * TS + t];
  __syncthreads();
  // r[30],r[31] junk-but-finite; overwritten at steps 0,1 before any read.

  #pragma unroll
  for (int R = 0; R < 2; ++R) {
    const int S = R * 32;
    #pragma unroll
    for (int i = 0; i < 8; ++i) {
      int f = i * 256 + t, ch = f >> 3, q = f & 7;
      float4 v = *(const float4*)(u + (size_t)(n0 + ch) * LCH + S + 4 * q);
      lds[(4 * q + 0) * TS + ch] = v.x;
      lds[(4 * q + 1) * TS + ch] = v.y;
      lds[(4 * q + 2) * TS + ch] = v.z;
      lds[(4 * q + 3) * TS + ch] = v.w;
    }
    __syncthreads();
    #pragma unroll
    for (int s = 0; s < 32; ++s) {
      float uv = lds[s * TS + t];               // own column only:
      lds[s * TS + t] = step6(r, wx, s, wf * uv);  // in-place, no hazard
    }
    __syncthreads();
    #pragma unroll
    for (int i = 0; i < 8; ++i) {
      int f = i * 256 + t, ch = f >> 3, q = f & 7;
      float4 w = make_float4(lds[(4 * q + 0) * TS + ch], lds[(4 * q + 1) * TS + ch],
                             lds[(4 * q + 2) * TS + ch], lds[(4 * q + 3) * TS + ch]);
      *(float4*)(out + (size_t)(n0 + ch) * LCH + S + 4 * q) = w;
    }
    __syncthreads();
  }
}

extern "C" void kernel_launch(void* const* d_in, const int* in_sizes, int n_in,
                              void* d_out, int out_size, void* d_ws, size_t ws_size,
                              hipStream_t stream) {
  const float* u  = (const float*)d_in[0];
  const float* x0 = (const float*)d_in[1];
  const float* Wx = (const float*)d_in[2];
  const float* Wf = (const float*)d_in[3];
  float* out = (float*)d_out;

  hipLaunchKernelGGL(k_passA, dim3(NBLK + 1),      dim3(256), 0, stream, u, Wx, Wf);
  hipLaunchKernelGGL(k_scan,  dim3(NB * 32 / 256), dim3(256), 0, stream, x0);
  hipLaunchKernelGGL(k_passC, dim3(NBLK),          dim3(256), 0, stream, u, Wx, Wf, out);
}

// Round 8
// 58.878 us; speedup vs baseline: 1.3787x; 1.3787x over previous
//
#include <hip/hip_runtime.h>

#define NB   8192
#define NT   2048
#define OBS  30
#define LCH  64               // chunk length
#define CCH  32               // chunks per row
#define RPB  4                // rows per block
#define TSTR 33               // tile stride (pad): all phases <=2-way banks

// C[t][i] = homogeneous output at local step t from unit state e_i, t<64.
__device__ float g_C[64 * 32];

// One recurrence step on a 32-slot register ring, 6 accumulator chains.
// Invariant: before step t, state s_t[i] lives at r[(t+i)&31], i=0..29.
__device__ __forceinline__ float step6(float (&r)[32], const float (&wx)[OBS],
                                       int j, float uwf) {
  float a0 = fmaf(wx[0], r[(j + 0) & 31], uwf);
  float a1 = wx[1] * r[(j + 1) & 31];
  float a2 = wx[2] * r[(j + 2) & 31];
  float a3 = wx[3] * r[(j + 3) & 31];
  float a4 = wx[4] * r[(j + 4) & 31];
  float a5 = wx[5] * r[(j + 5) & 31];
  #pragma unroll
  for (int i = 6; i < OBS; i += 6) {
    a0 = fmaf(wx[i],     r[(j + i)     & 31], a0);
    a1 = fmaf(wx[i + 1], r[(j + i + 1) & 31], a1);
    a2 = fmaf(wx[i + 2], r[(j + i + 2) & 31], a2);
    a3 = fmaf(wx[i + 3], r[(j + i + 3) & 31], a3);
    a4 = fmaf(wx[i + 4], r[(j + i + 4) & 31], a4);
    a5 = fmaf(wx[i + 5], r[(j + i + 5) & 31], a5);
  }
  float out = ((a0 + a1) + (a2 + a3)) + (a4 + a5);
  r[(j + 30) & 31] = out;
  return out;
}

// ---- C matrix: 30 unit-state homogeneous chains, lane i -> column i ----
__global__ void k_C(const float* __restrict__ Wx) {
  const int k = threadIdx.x;
  if (k >= 32) return;
  float wx[OBS];
  #pragma unroll
  for (int i = 0; i < OBS; ++i) wx[i] = Wx[i];
  float r[32];
  #pragma unroll
  for (int i = 0; i < 32; ++i) r[i] = (k < OBS && i == k) ? 1.f : 0.f;
  #pragma unroll
  for (int j = 0; j < 32; ++j) g_C[j * 32 + k] = step6(r, wx, j, 0.f);
  #pragma unroll
  for (int j = 0; j < 32; ++j) g_C[(32 + j) * 32 + k] = step6(r, wx, j, 0.f);
}

// ---- fused: particular recurrence + scan + correction, one kernel ----
// Block: 128 threads = 4 groups of 32 lanes; group g owns row row0+g.
// Lane k: phase2 runs chunk k's zero-init recurrence; phase3 owns outputs
// t=k and t=k+32 of each chunk c (serial over c, state via LDS slot).
__global__ void __launch_bounds__(128) k_fused(const float* __restrict__ u,
                                               const float* __restrict__ x0,
                                               const float* __restrict__ Wx,
                                               const float* __restrict__ Wf,
                                               float* __restrict__ out) {
  __shared__ float tile[RPB * 64 * TSTR];   // 33.8 KB: [row][t][c]
  __shared__ float sbuf[RPB * 32];          // per-group state slot
  const int tid  = threadIdx.x;
  const int g    = tid >> 5, k = tid & 31;
  const int row0 = blockIdx.x * RPB;

  float wx[OBS];
  #pragma unroll
  for (int i = 0; i < OBS; ++i) wx[i] = Wx[i];
  const float wf = Wf[0];

  // ---- phase 1: cooperative coalesced load of 4 u rows -> transposed tile
  const float* ub = u + (size_t)row0 * NT;
  #pragma unroll
  for (int i = 0; i < 16; ++i) {
    int v  = i * 128 + tid;            // float4 id 0..2047
    int rr = v >> 9;                   // row 0..3
    int p  = v & 511;                  // float4 within row
    float4 d = *(const float4*)(ub + (size_t)rr * NT + 4 * p);
    int c = p >> 4, t = 4 * (p & 15);
    float* tp = &tile[(rr * 64 + t) * TSTR + c];
    tp[0 * TSTR] = d.x; tp[1 * TSTR] = d.y;
    tp[2 * TSTR] = d.z; tp[3 * TSTR] = d.w;
  }
  __syncthreads();

  // ---- phase 2: zero-init particular recurrence, in-place in tile
  {
    float r[32];
    #pragma unroll
    for (int i = 0; i < 32; ++i) r[i] = 0.f;
    float* tcol = &tile[g * 64 * TSTR + k];
    #pragma unroll
    for (int q = 0; q < 2; ++q)
      #pragma unroll
      for (int j = 0; j < 32; ++j) {
        float uv = tcol[(q * 32 + j) * TSTR];
        tcol[(q * 32 + j) * TSTR] = step6(r, wx, j, wf * uv);
      }
  }

  // ---- phase 3 prep: C rows into registers, x0 into slot
  float c0[OBS], c1[OBS];
  #pragma unroll
  for (int i = 0; i < OBS; ++i) c0[i] = g_C[k * 32 + i];
  #pragma unroll
  for (int i = 0; i < OBS; ++i) c1[i] = g_C[(k + 32) * 32 + i];
  sbuf[g * 32 + k] = (k < OBS) ? x0[(size_t)(row0 + g) * OBS + k] : 0.f;
  __syncthreads();

  // ---- phase 3: serial over chunks; state lives in the group slot
  float* ob = out + (size_t)(row0 + g) * NT;
  float* sl = &sbuf[g * 32];
  const float* trow = &tile[g * 64 * TSTR];
  #pragma unroll 1
  for (int c = 0; c < CCH; ++c) {
    float sv[32];
    #pragma unroll
    for (int q = 0; q < 8; ++q) {      // broadcast reads: conflict-free
      float4 v = *(const float4*)(&sl[4 * q]);
      sv[4 * q] = v.x; sv[4 * q + 1] = v.y;
      sv[4 * q + 2] = v.z; sv[4 * q + 3] = v.w;
    }
    float p0 = trow[k * TSTR + c];            // particular out, t=k
    float p1 = trow[(k + 32) * TSTR + c];     // particular out, t=k+32
    // serial-path dot first: true out at t=k+32 feeds next state
    float t1, t0;
    {
      float a0 = fmaf(c1[0], sv[0], p1);
      float a1 = c1[1] * sv[1];
      float a2 = c1[2] * sv[2];
      float a3 = c1[3] * sv[3];
      #pragma unroll
      for (int i = 4; i < 28; i += 4) {
        a0 = fmaf(c1[i],     sv[i],     a0);
        a1 = fmaf(c1[i + 1], sv[i + 1], a1);
        a2 = fmaf(c1[i + 2], sv[i + 2], a2);
        a3 = fmaf(c1[i + 3], sv[i + 3], a3);
      }
      a0 = fmaf(c1[28], sv[28], a0);
      a1 = fmaf(c1[29], sv[29], a1);
      t1 = (a0 + a1) + (a2 + a3);
    }
    if (k >= 2) sl[k - 2] = t1;    // s_next[i] = true_out[34+i], i=k-2
    {
      float a0 = fmaf(c0[0], sv[0], p0);
      float a1 = c0[1] * sv[1];
      float a2 = c0[2] * sv[2];
      float a3 = c0[3] * sv[3];
      #pragma unroll
      for (int i = 4; i < 28; i += 4) {
        a0 = fmaf(c0[i],     sv[i],     a0);
        a1 = fmaf(c0[i + 1], sv[i + 1], a1);
        a2 = fmaf(c0[i + 2], sv[i + 2], a2);
        a3 = fmaf(c0[i + 3], sv[i + 3], a3);
      }
      a0 = fmaf(c0[28], sv[28], a0);
      a1 = fmaf(c0[29], sv[29], a1);
      t0 = (a0 + a1) + (a2 + a3);
    }
    ob[c * 64 + k]      = t0;      // coalesced 128B per half-wave
    ob[c * 64 + 32 + k] = t1;
    // next iteration's sv read is ordered after sl write (same-wave DS order)
  }
}

extern "C" void kernel_launch(void* const* d_in, const int* in_sizes, int n_in,
                              void* d_out, int out_size, void* d_ws, size_t ws_size,
                              hipStream_t stream) {
  const float* u  = (const float*)d_in[0];
  const float* x0 = (const float*)d_in[1];
  const float* Wx = (const float*)d_in[2];
  const float* Wf = (const float*)d_in[3];
  float* out = (float*)d_out;

  hipLaunchKernelGGL(k_C,     dim3(1),        dim3(64),  0, stream, Wx);
  hipLaunchKernelGGL(k_fused, dim3(NB / RPB), dim3(128), 0, stream,
                     u, x0, Wx, Wf, out);
}

// Round 9
// 54.566 us; speedup vs baseline: 1.4877x; 1.0790x over previous
//
#include <hip/hip_runtime.h>

#define NB   8192
#define NT   2048
#define OBS  30
#define LCH  32               // chunk length
#define CPH  32               // chunks per half-row
#define HALF 1024             // NT/2
#define RPB  4                // rows per block
#define CSTR 36               // chunk stride (floats): 144B, 16B-aligned

// One recurrence step on a 32-slot register ring, 6 accumulator chains.
// Invariant: before step t, state s_t[i] lives at r[(t+i)&31], i=0..29.
// j == t mod 32 must be a compile-time constant (callers fully unroll).
__device__ __forceinline__ float step6(float (&r)[32], const float (&wx)[OBS],
                                       int j, float uwf) {
  float a0 = fmaf(wx[0], r[(j + 0) & 31], uwf);
  float a1 = wx[1] * r[(j + 1) & 31];
  float a2 = wx[2] * r[(j + 2) & 31];
  float a3 = wx[3] * r[(j + 3) & 31];
  float a4 = wx[4] * r[(j + 4) & 31];
  float a5 = wx[5] * r[(j + 5) & 31];
  #pragma unroll
  for (int i = 6; i < OBS; i += 6) {
    a0 = fmaf(wx[i],     r[(j + i)     & 31], a0);
    a1 = fmaf(wx[i + 1], r[(j + i + 1) & 31], a1);
    a2 = fmaf(wx[i + 2], r[(j + i + 2) & 31], a2);
    a3 = fmaf(wx[i + 3], r[(j + i + 3) & 31], a3);
    a4 = fmaf(wx[i + 4], r[(j + i + 4) & 31], a4);
    a5 = fmaf(wx[i + 5], r[(j + i + 5) & 31], a5);
  }
  float out = ((a0 + a1) + (a2 + a3)) + (a4 + a5);
  r[(j + 30) & 31] = out;
  return out;
}

// Fully fused: C-matrix + particular recurrence + chunk scan + correction.
// Block: 128 threads = 4 groups of 32 lanes; group g owns row row0+g.
// Row processed as two half-row tiles of 32 chunks x 32 steps.
__global__ void __launch_bounds__(128, 4)
k_fused(const float* __restrict__ u, const float* __restrict__ x0,
        const float* __restrict__ Wx, const float* __restrict__ Wf,
        float* __restrict__ out) {
  __shared__ float tile[RPB * CPH * CSTR];   // 18.4 KB: [row][chunk][36]
  __shared__ float sbuf[RPB * 32];           // per-group running state slot
  const int tid  = threadIdx.x;
  const int g    = tid >> 5, k = tid & 31;
  const int row0 = blockIdx.x * RPB;

  float wx[OBS];
  #pragma unroll
  for (int i = 0; i < OBS; ++i) wx[i] = Wx[i];
  const float wf = Wf[0];

  // ---- issue h=0 global loads (consumed after phase 0 hides their latency)
  float4 stg[8];
  const float* ub = u + (size_t)row0 * NT;
  #pragma unroll
  for (int i = 0; i < 8; ++i) {
    int v = i * 128 + tid, rr = v >> 8, p = v & 255;
    stg[i] = *(const float4*)(ub + (size_t)rr * NT + 4 * p);
  }

  // ---- phase 0: C[t][i] = homog output at step t from e_i (lane i = column)
  // Redundant across groups; tid<32 writes. Overlaid on tile (dead region).
  {
    float r[32];
    #pragma unroll
    for (int i = 0; i < 32; ++i) r[i] = (k < OBS && i == k) ? 1.f : 0.f;
    #pragma unroll
    for (int j = 0; j < 32; ++j) {
      float o = step6(r, wx, j, 0.f);
      if (tid < 32) tile[j * 33 + k] = o;    // C row j (stride 33: no conflict)
    }
  }
  __syncthreads();
  float c0[OBS];                             // my C row: C[k][0..29]
  #pragma unroll
  for (int i = 0; i < OBS; ++i) c0[i] = tile[k * 33 + i];
  if (k < OBS) sbuf[g * 32 + k] = x0[(size_t)(row0 + g) * OBS + k];
  __syncthreads();                           // C reads done; tile reusable

  float* sl = &sbuf[g * 32];

  #pragma unroll 1
  for (int h = 0; h < 2; ++h) {
    // ---- stage this half's u into chunk-major tile (b128 writes)
    #pragma unroll
    for (int i = 0; i < 8; ++i) {
      int v = i * 128 + tid, rr = v >> 8, p = v & 255;
      int c = p >> 3, t = 4 * (p & 7);
      *(float4*)(&tile[(rr * CPH + c) * CSTR + t]) = stg[i];
    }
    __syncthreads();

    // ---- phase 2: zero-init particular recurrence, in-place (b128 r/w)
    {
      float r[32];
      #pragma unroll
      for (int i = 0; i < 32; ++i) r[i] = 0.f;
      float* tc = &tile[(g * CPH + k) * CSTR];
      #pragma unroll
      for (int q = 0; q < 8; ++q) {
        float4 u4 = *(const float4*)(tc + 4 * q);
        float4 o4;
        o4.x = step6(r, wx, 4 * q + 0, wf * u4.x);
        o4.y = step6(r, wx, 4 * q + 1, wf * u4.y);
        o4.z = step6(r, wx, 4 * q + 2, wf * u4.z);
        o4.w = step6(r, wx, 4 * q + 3, wf * u4.w);
        *(float4*)(tc + 4 * q) = o4;
      }
    }

    // ---- issue next half's global loads: land under phase 3's serial scan
    if (h == 0) {
      #pragma unroll
      for (int i = 0; i < 8; ++i) {
        int v = i * 128 + tid, rr = v >> 8, p = v & 255;
        stg[i] = *(const float4*)(ub + (size_t)rr * NT + HALF + 4 * p);
      }
    }
    __builtin_amdgcn_wave_barrier();   // order phase2 DS writes vs phase3 reads

    // ---- phase 3: serial over chunks; state in group slot (wave-synchronous)
    float* ob = out + (size_t)(row0 + g) * NT + h * HALF;
    const float* tg = &tile[g * CPH * CSTR];
    #pragma unroll 1
    for (int c = 0; c < CPH; ++c) {
      float sv[32];
      #pragma unroll
      for (int q = 0; q < 8; ++q) {          // broadcast b128: conflict-free
        float4 v = *(const float4*)(sl + 4 * q);
        sv[4 * q] = v.x; sv[4 * q + 1] = v.y;
        sv[4 * q + 2] = v.z; sv[4 * q + 3] = v.w;
      }
      float p0 = tg[c * CSTR + k];           // particular out, lane-contiguous
      float a0 = fmaf(c0[0], sv[0], p0);
      float a1 = c0[1] * sv[1];
      float a2 = c0[2] * sv[2];
      float a3 = c0[3] * sv[3];
      #pragma unroll
      for (int i = 4; i < 28; i += 4) {
        a0 = fmaf(c0[i],     sv[i],     a0);
        a1 = fmaf(c0[i + 1], sv[i + 1], a1);
        a2 = fmaf(c0[i + 2], sv[i + 2], a2);
        a3 = fmaf(c0[i + 3], sv[i + 3], a3);
      }
      a0 = fmaf(c0[28], sv[28], a0);
      a1 = fmaf(c0[29], sv[29], a1);
      float t0 = (a0 + a1) + (a2 + a3);      // true output at t = c*32 + k
      if (k >= 2) sl[k - 2] = t0;            // s_next[i] = out[2+i]
      ob[c * 32 + k] = t0;                   // coalesced 128B per group
      __builtin_amdgcn_wave_barrier();       // fence slot write vs next read
    }
    __syncthreads();                         // tile reuse for next half
  }
}

extern "C" void kernel_launch(void* const* d_in, const int* in_sizes, int n_in,
                              void* d_out, int out_size, void* d_ws, size_t ws_size,
                              hipStream_t stream) {
  const float* u  = (const float*)d_in[0];
  const float* x0 = (const float*)d_in[1];
  const float* Wx = (const float*)d_in[2];
  const float* Wf = (const float*)d_in[3];
  float* out = (float*)d_out;

  hipLaunchKernelGGL(k_fused, dim3(NB / RPB), dim3(128), 0, stream,
                     u, x0, Wx, Wf, out);
}